// Round 16
// baseline (367.382 us; speedup 1.0000x reference)
//
#include <hip/hip_runtime.h>

// weighted_graph_conv, round 16:
//  - gather split into 2 sequential dispatches by t-pair: per-phase nfb working
//    set 12.8MB (vs 25.6) -> higher L2 hit. Wave processes 2 edges/step
//    (lane-halves), scalar rec loads kept, 4-pair unroll = 8 rows in flight
//    (same MLP as R15's 8-wide). No dispatch-order assumptions (unlike R10).
//  - transform grid 1024 -> 2048 blocks (was 3 TB/s with latency slack)
//  - rest identical to R15 (fused transform+hist, fused scan, fill)

#define F_DIM 64
#define TF 256  // T*F

typedef __attribute__((ext_vector_type(8))) short bf16x8;
typedef __attribute__((ext_vector_type(4))) float f32x4;
union frag_u { bf16x8 v; unsigned short s[8]; };

__device__ __forceinline__ unsigned short f2bf(float x) {
  unsigned u = __float_as_uint(x);
  return (unsigned short)((u + 0x7FFF + ((u >> 16) & 1)) >> 16);  // RNE
}
__device__ __forceinline__ float bf2f(unsigned short b) {
  return __uint_as_float(((unsigned)b) << 16);
}

// Fused MFMA transform + grid-stride histogram.
__global__ __launch_bounds__(256) void transform_hist_kernel(
    const float4* __restrict__ nf4, const float* __restrict__ W,
    unsigned short* __restrict__ nfb, int nrows,
    const int* __restrict__ dst, int* __restrict__ cnt, int E) {
  int lane = threadIdx.x & 63;
  int l15 = lane & 15, lg = lane >> 4;
  int wid = (blockIdx.x * 256 + threadIdx.x) >> 6;
  int nw = (gridDim.x * 256) >> 6;

  frag_u a[4][2];   // A = W, staged once per wave
  #pragma unroll
  for (int ot = 0; ot < 4; ++ot) {
    #pragma unroll
    for (int kh = 0; kh < 2; ++kh) {
      const float* wp = W + (ot * 16 + l15) * 64 + kh * 32 + lg * 8;
      float4 v0 = *reinterpret_cast<const float4*>(wp);
      float4 v1 = *reinterpret_cast<const float4*>(wp + 4);
      a[ot][kh].s[0] = f2bf(v0.x); a[ot][kh].s[1] = f2bf(v0.y);
      a[ot][kh].s[2] = f2bf(v0.z); a[ot][kh].s[3] = f2bf(v0.w);
      a[ot][kh].s[4] = f2bf(v1.x); a[ot][kh].s[5] = f2bf(v1.y);
      a[ot][kh].s[6] = f2bf(v1.z); a[ot][kh].s[7] = f2bf(v1.w);
    }
  }

  int ntiles = (nrows + 15) >> 4;
  for (int tile = wid; tile < ntiles; tile += nw) {
    int r = tile * 16 + l15;
    int rc = min(r, nrows - 1);
    const float4* bp = nf4 + (size_t)rc * 16 + lg * 2;
    float4 v0 = bp[0], v1 = bp[1];
    float4 v2 = bp[8], v3 = bp[9];
    frag_u b0, b1;
    b0.s[0] = f2bf(v0.x); b0.s[1] = f2bf(v0.y);
    b0.s[2] = f2bf(v0.z); b0.s[3] = f2bf(v0.w);
    b0.s[4] = f2bf(v1.x); b0.s[5] = f2bf(v1.y);
    b0.s[6] = f2bf(v1.z); b0.s[7] = f2bf(v1.w);
    b1.s[0] = f2bf(v2.x); b1.s[1] = f2bf(v2.y);
    b1.s[2] = f2bf(v2.z); b1.s[3] = f2bf(v2.w);
    b1.s[4] = f2bf(v3.x); b1.s[5] = f2bf(v3.y);
    b1.s[6] = f2bf(v3.z); b1.s[7] = f2bf(v3.w);

    f32x4 acc[4];
    #pragma unroll
    for (int ot = 0; ot < 4; ++ot) {
      f32x4 z = {0.f, 0.f, 0.f, 0.f};
      acc[ot] = __builtin_amdgcn_mfma_f32_16x16x32_bf16(a[ot][0].v, b0.v, z, 0, 0, 0);
      acc[ot] = __builtin_amdgcn_mfma_f32_16x16x32_bf16(a[ot][1].v, b1.v, acc[ot], 0, 0, 0);
    }
    if (r < nrows) {
      #pragma unroll
      for (int ot = 0; ot < 4; ++ot) {
        ushort4 u = make_ushort4(f2bf(acc[ot][0]), f2bf(acc[ot][1]),
                                 f2bf(acc[ot][2]), f2bf(acc[ot][3]));
        *reinterpret_cast<ushort4*>(
            &nfb[(size_t)r * F_DIM + ot * 16 + lg * 4]) = u;
      }
    }
  }

  int gtid = blockIdx.x * 256 + threadIdx.x;
  int gsz = gridDim.x * 256;
  for (int e = gtid; e < E; e += gsz) atomicAdd(&cnt[dst[e]], 1);
}

// Block scan + last-block bsum scan (R15, unchanged — passed validation).
__global__ __launch_bounds__(1024) void scan_kernel(
    const int* __restrict__ cnt, int* __restrict__ off, int* __restrict__ bsum,
    int* __restrict__ sync, int N) {
  __shared__ int wsum[16];
  __shared__ int isLast;
  int tid = threadIdx.x;
  if (tid == 0) isLast = 0;
  int i = blockIdx.x * 1024 + tid;
  int v = (i < N) ? cnt[i] : 0;
  int lane = tid & 63;
  int incl = v;
  #pragma unroll
  for (int s = 1; s < 64; s <<= 1) {
    int t = __shfl_up(incl, s, 64);
    if (lane >= s) incl += t;
  }
  int w = tid >> 6;
  if (lane == 63) wsum[w] = incl;
  __syncthreads();
  if (w == 0) {
    int x = (lane < 16) ? wsum[lane] : 0;
    #pragma unroll
    for (int s = 1; s < 16; s <<= 1) {
      int t = __shfl_up(x, s, 64);
      if (lane >= s) x += t;
    }
    if (lane < 16) wsum[lane] = x;
  }
  __syncthreads();
  int wpre = (w == 0) ? 0 : wsum[w - 1];
  if (i < N) off[i] = wpre + incl - v;

  if (tid == 1023) {
    atomicExch(&bsum[blockIdx.x], wpre + incl);
    __threadfence();
    if (atomicAdd(sync, 1) == (int)gridDim.x - 1) isLast = 1;
  }
  __syncthreads();
  if (isLast && tid < 64) {
    int nb = gridDim.x;
    int bv = (tid < nb) ? atomicAdd(&bsum[tid], 0) : 0;
    int binc = bv;
    #pragma unroll
    for (int s = 1; s < 64; s <<= 1) {
      int t = __shfl_up(binc, s, 64);
      if (lane >= s) binc += t;
    }
    if (tid < nb) atomicExch(&bsum[tid], binc - bv);
  }
}

// CSR record: x=src, y=(w1|w0) bf16 pair, z=(w3|w2) bf16 pair, w=0.
__global__ __launch_bounds__(256) void fill_kernel(
    const int* __restrict__ dst, const int* __restrict__ src,
    const float* __restrict__ ew, const int* __restrict__ off,
    const int* __restrict__ bsum, int* __restrict__ cnt,
    uint4* __restrict__ rec, int E) {
  int e = blockIdx.x * 256 + threadIdx.x;
  if (e < E) {
    int d = dst[e];
    int pos = off[d] + bsum[d >> 10] + atomicSub(&cnt[d], 1) - 1;
    unsigned w0 = f2bf(ew[e]),         w1 = f2bf(ew[E + e]);
    unsigned w2 = f2bf(ew[2 * E + e]), w3 = f2bf(ew[3 * E + e]);
    uint4 r;
    r.x = (unsigned)src[e];
    r.y = (w1 << 16) | w0;
    r.z = (w3 << 16) | w2;
    r.w = 0;
    rec[pos] = r;
  }
}

// t-pair gather: dispatch tp=0 covers t in {0,1}, tp=1 covers {2,3}.
// Wave = node; lanes: g=lane>>5 (edge pair half), tl=(lane>>4)&1, q=lane&15.
// Per step: 2 edges (scalar rec loads, broadcast+select), each lane reads one
// ushort4 of a 256B half-row. 4-pair unroll = 8 rows in flight. Cross-group
// shfl_xor(32) reduce; g==0 lanes add bias and write the 256B out half-slice.
__global__ __launch_bounds__(256) void gather_tp_kernel(
    const ushort4* __restrict__ nfb, const uint4* __restrict__ rec,
    const int* __restrict__ off, const int* __restrict__ bsum,
    const float4* __restrict__ bias4, float4* __restrict__ out4,
    int N, int E, int tp) {
  int idx = blockIdx.x * 256 + threadIdx.x;
  int n = idx >> 6;
  if (n >= N) return;
  n = __builtin_amdgcn_readfirstlane(n);
  int lane = idx & 63;
  int g = lane >> 5;
  int tl = (lane >> 4) & 1;
  int q = lane & 15;
  int t = tp * 2 + tl;
  int wshift = tl << 4;
  int beg = off[n] + bsum[n >> 10];
  int end = (n + 1 < N) ? off[n + 1] + bsum[(n + 1) >> 10] : E;
  beg = __builtin_amdgcn_readfirstlane(beg);
  end = __builtin_amdgcn_readfirstlane(end);

  float4 acc = make_float4(0.f, 0.f, 0.f, 0.f);
  int p = beg;
  for (; p + 8 <= end; p += 8) {         // 4 pairs per iteration
    uint4 rr[8];
    #pragma unroll
    for (int j = 0; j < 8; ++j) rr[j] = rec[p + j];
    float w[4];
    ushort4 v[4];
    #pragma unroll
    for (int j = 0; j < 4; ++j) {
      uint4 rm = g ? rr[2 * j + 1] : rr[2 * j];
      unsigned wp = tp ? rm.z : rm.y;
      w[j] = __uint_as_float(((wp >> wshift) & 0xFFFFu) << 16);
      v[j] = nfb[(size_t)rm.x * 64 + t * 16 + q];
    }
    #pragma unroll
    for (int j = 0; j < 4; ++j) {
      acc.x += w[j] * bf2f(v[j].x);
      acc.y += w[j] * bf2f(v[j].y);
      acc.z += w[j] * bf2f(v[j].z);
      acc.w += w[j] * bf2f(v[j].w);
    }
  }
  for (; p + 2 <= end; p += 2) {         // pair tail
    uint4 r0 = rec[p], r1 = rec[p + 1];
    uint4 rm = g ? r1 : r0;
    unsigned wp = tp ? rm.z : rm.y;
    float w = __uint_as_float(((wp >> wshift) & 0xFFFFu) << 16);
    ushort4 v = nfb[(size_t)rm.x * 64 + t * 16 + q];
    acc.x += w * bf2f(v.x); acc.y += w * bf2f(v.y);
    acc.z += w * bf2f(v.z); acc.w += w * bf2f(v.w);
  }
  if (p < end) {                         // single tail: group 1 contributes 0
    uint4 rm = rec[p];
    unsigned wp = tp ? rm.z : rm.y;
    float w = __uint_as_float(((wp >> wshift) & 0xFFFFu) << 16);
    if (g) w = 0.f;
    ushort4 v = nfb[(size_t)rm.x * 64 + t * 16 + q];
    acc.x += w * bf2f(v.x); acc.y += w * bf2f(v.y);
    acc.z += w * bf2f(v.z); acc.w += w * bf2f(v.w);
  }

  acc.x += __shfl_xor(acc.x, 32); acc.y += __shfl_xor(acc.y, 32);
  acc.z += __shfl_xor(acc.z, 32); acc.w += __shfl_xor(acc.w, 32);

  if (g == 0) {
    float4 b = bias4[q];
    float4 res = make_float4(acc.x + b.x, acc.y + b.y, acc.z + b.z, acc.w + b.w);
    out4[(size_t)n * 64 + t * 16 + q] = res;
  }
}

// ---- f32 fallback path (small ws) ----
__global__ __launch_bounds__(256) void hist_kernel(
    const int* __restrict__ dst, int* __restrict__ cnt, int E) {
  int e = blockIdx.x * 256 + threadIdx.x;
  if (e < E) atomicAdd(&cnt[dst[e]], 1);
}

__global__ __launch_bounds__(256) void gather_f32_kernel(
    const float4* __restrict__ nf4, const uint4* __restrict__ rec,
    const int* __restrict__ off, const int* __restrict__ bsum,
    float4* __restrict__ h4, int N, int E) {
  int idx = blockIdx.x * 256 + threadIdx.x;
  int n = idx >> 6;
  if (n >= N) return;
  int r = idx & 63, t = r >> 4, q = r & 15;
  int wsel = t >> 1;
  int wshift = (t & 1) << 4;
  int beg = off[n] + bsum[n >> 10];
  int end = (n + 1 < N) ? off[n + 1] + bsum[(n + 1) >> 10] : E;
  float4 acc = make_float4(0.f, 0.f, 0.f, 0.f);
  for (int p = beg; p < end; ++p) {
    uint4 rr = rec[p];
    float w = __uint_as_float(((wsel ? rr.z : rr.y) >> wshift) << 16);
    float4 v = nf4[(size_t)rr.x * 64 + t * 16 + q];
    acc.x += w * v.x; acc.y += w * v.y; acc.z += w * v.z; acc.w += w * v.w;
  }
  h4[(size_t)n * 64 + t * 16 + q] = acc;
}

__global__ __launch_bounds__(256) void linear_kernel(
    float* __restrict__ h, const float* __restrict__ W,
    const float* __restrict__ bias, int nrows) {
  __shared__ float Wt[64 * 65];
  __shared__ float rows[4][64];
  int tid = threadIdx.x;
  for (int i = tid; i < 4096; i += 256) Wt[(i & 63) * 65 + (i >> 6)] = W[i];
  int rr = tid >> 6, o = tid & 63;
  float b = bias[o];
  int rbase = blockIdx.x * 32;
  for (int r0 = 0; r0 < 32; r0 += 4) {
    int row = rbase + r0 + rr;
    __syncthreads();
    if (row < nrows) rows[rr][o] = h[(size_t)row * F_DIM + o];
    __syncthreads();
    if (row < nrows) {
      float acc = b;
      #pragma unroll
      for (int f = 0; f < 64; ++f) acc += rows[rr][f] * Wt[f * 65 + o];
      h[(size_t)row * F_DIM + o] = acc;
    }
  }
}

extern "C" void kernel_launch(void* const* d_in, const int* in_sizes, int n_in,
                              void* d_out, int out_size, void* d_ws, size_t ws_size,
                              hipStream_t stream) {
  const float* nf   = (const float*)d_in[0];
  const float* ew   = (const float*)d_in[1];
  const int*   src  = (const int*)d_in[2];
  const int*   dst  = (const int*)d_in[3];
  const float* W    = (const float*)d_in[4];
  const float* bias = (const float*)d_in[5];
  float* out = (float*)d_out;

  int E = in_sizes[2];
  int N = out_size / TF;
  int nrows = out_size / F_DIM;   // N*T
  int nfelems = nrows * F_DIM;

  // ws layout: [cnt N][sync 1][off N+1][bsum 64] | rec uint4[E] | nfb (512B-aligned)
  char* wsb = (char*)d_ws;
  int* cnt  = (int*)wsb;
  int* sync = cnt + N;
  int* off  = sync + 1;
  int* bsum = off + (N + 1);
  size_t ofs = ((size_t)(2 * N + 2 + 64) * 4 + 15) & ~(size_t)15;
  uint4* rec = (uint4*)(wsb + ofs);           ofs += (size_t)E * 16;
  ofs = (ofs + 511) & ~(size_t)511;
  unsigned short* nfb = (unsigned short*)(wsb + ofs);
  size_t need_bf16 = ofs + (size_t)nfelems * 2;
  bool use_bf16 = ws_size >= need_bf16;

  (void)hipMemsetAsync(cnt, 0, (size_t)(N + 1) * sizeof(int), stream);  // cnt + sync

  int eblk = (E + 255) / 256;
  int sblk = (N + 1023) / 1024;   // <= 64 required by fused scan (N <= 65536)
  int gblk = (N * 64 + 255) / 256;

  if (use_bf16) {
    transform_hist_kernel<<<2048, 256, 0, stream>>>(
        (const float4*)nf, W, nfb, nrows, dst, cnt, E);
    scan_kernel<<<sblk, 1024, 0, stream>>>(cnt, off, bsum, sync, N);
    fill_kernel<<<eblk, 256, 0, stream>>>(dst, src, ew, off, bsum, cnt, rec, E);
    gather_tp_kernel<<<gblk, 256, 0, stream>>>(
        (const ushort4*)nfb, rec, off, bsum, (const float4*)bias,
        (float4*)out, N, E, 0);
    gather_tp_kernel<<<gblk, 256, 0, stream>>>(
        (const ushort4*)nfb, rec, off, bsum, (const float4*)bias,
        (float4*)out, N, E, 1);
  } else {
    hist_kernel<<<eblk, 256, 0, stream>>>(dst, cnt, E);
    scan_kernel<<<sblk, 1024, 0, stream>>>(cnt, off, bsum, sync, N);
    fill_kernel<<<eblk, 256, 0, stream>>>(dst, src, ew, off, bsum, cnt, rec, E);
    gather_f32_kernel<<<gblk, 256, 0, stream>>>(
        (const float4*)nf, rec, off, bsum, (float4*)out, N, E);
    linear_kernel<<<(nrows + 31) / 32, 256, 0, stream>>>(out, W, bias, nrows);
  }
}

// Round 17
// 161.239 us; speedup vs baseline: 2.2785x; 2.2785x over previous
//
#include <hip/hip_runtime.h>

// weighted_graph_conv, round 17: REVERT to R15 (best validated, ~162us).
// R16's t-pair gather split regressed 2.3x: per-dispatch read FETCH dropped
// 188->134MB as predicted, but half-masked partial-row stores caused ~25x
// WRITE amplification (50->643MB/dispatch) — second independent failure of
// t-phasing. Pipeline is fabric-bound at each stage; schedules R13/R14/R15
// all converge 160-163us. This is the R15 source unchanged.

#define F_DIM 64
#define TF 256  // T*F

typedef __attribute__((ext_vector_type(8))) short bf16x8;
typedef __attribute__((ext_vector_type(4))) float f32x4;
union frag_u { bf16x8 v; unsigned short s[8]; };

__device__ __forceinline__ unsigned short f2bf(float x) {
  unsigned u = __float_as_uint(x);
  return (unsigned short)((u + 0x7FFF + ((u >> 16) & 1)) >> 16);  // RNE
}
__device__ __forceinline__ float bf2f(unsigned short b) {
  return __uint_as_float(((unsigned)b) << 16);
}

// Fused MFMA transform + grid-stride histogram.
__global__ __launch_bounds__(256) void transform_hist_kernel(
    const float4* __restrict__ nf4, const float* __restrict__ W,
    unsigned short* __restrict__ nfb, int nrows,
    const int* __restrict__ dst, int* __restrict__ cnt, int E) {
  int lane = threadIdx.x & 63;
  int l15 = lane & 15, lg = lane >> 4;
  int wid = (blockIdx.x * 256 + threadIdx.x) >> 6;
  int nw = (gridDim.x * 256) >> 6;

  frag_u a[4][2];   // A = W, staged once per wave
  #pragma unroll
  for (int ot = 0; ot < 4; ++ot) {
    #pragma unroll
    for (int kh = 0; kh < 2; ++kh) {
      const float* wp = W + (ot * 16 + l15) * 64 + kh * 32 + lg * 8;
      float4 v0 = *reinterpret_cast<const float4*>(wp);
      float4 v1 = *reinterpret_cast<const float4*>(wp + 4);
      a[ot][kh].s[0] = f2bf(v0.x); a[ot][kh].s[1] = f2bf(v0.y);
      a[ot][kh].s[2] = f2bf(v0.z); a[ot][kh].s[3] = f2bf(v0.w);
      a[ot][kh].s[4] = f2bf(v1.x); a[ot][kh].s[5] = f2bf(v1.y);
      a[ot][kh].s[6] = f2bf(v1.z); a[ot][kh].s[7] = f2bf(v1.w);
    }
  }

  int ntiles = (nrows + 15) >> 4;
  for (int tile = wid; tile < ntiles; tile += nw) {
    int r = tile * 16 + l15;
    int rc = min(r, nrows - 1);
    const float4* bp = nf4 + (size_t)rc * 16 + lg * 2;
    float4 v0 = bp[0], v1 = bp[1];
    float4 v2 = bp[8], v3 = bp[9];
    frag_u b0, b1;
    b0.s[0] = f2bf(v0.x); b0.s[1] = f2bf(v0.y);
    b0.s[2] = f2bf(v0.z); b0.s[3] = f2bf(v0.w);
    b0.s[4] = f2bf(v1.x); b0.s[5] = f2bf(v1.y);
    b0.s[6] = f2bf(v1.z); b0.s[7] = f2bf(v1.w);
    b1.s[0] = f2bf(v2.x); b1.s[1] = f2bf(v2.y);
    b1.s[2] = f2bf(v2.z); b1.s[3] = f2bf(v2.w);
    b1.s[4] = f2bf(v3.x); b1.s[5] = f2bf(v3.y);
    b1.s[6] = f2bf(v3.z); b1.s[7] = f2bf(v3.w);

    f32x4 acc[4];
    #pragma unroll
    for (int ot = 0; ot < 4; ++ot) {
      f32x4 z = {0.f, 0.f, 0.f, 0.f};
      acc[ot] = __builtin_amdgcn_mfma_f32_16x16x32_bf16(a[ot][0].v, b0.v, z, 0, 0, 0);
      acc[ot] = __builtin_amdgcn_mfma_f32_16x16x32_bf16(a[ot][1].v, b1.v, acc[ot], 0, 0, 0);
    }
    if (r < nrows) {
      #pragma unroll
      for (int ot = 0; ot < 4; ++ot) {
        ushort4 u = make_ushort4(f2bf(acc[ot][0]), f2bf(acc[ot][1]),
                                 f2bf(acc[ot][2]), f2bf(acc[ot][3]));
        *reinterpret_cast<ushort4*>(
            &nfb[(size_t)r * F_DIM + ot * 16 + lg * 4]) = u;
      }
    }
  }

  // fused histogram (grid-stride)
  int gtid = blockIdx.x * 256 + threadIdx.x;
  int gsz = gridDim.x * 256;
  for (int e = gtid; e < E; e += gsz) atomicAdd(&cnt[dst[e]], 1);
}

// Block-local exclusive scan + per-block totals; LAST finishing block also
// exclusive-scans bsum in place (wave 0, shfl) -> scanB launch eliminated.
__global__ __launch_bounds__(1024) void scan_kernel(
    const int* __restrict__ cnt, int* __restrict__ off, int* __restrict__ bsum,
    int* __restrict__ sync, int N) {
  __shared__ int wsum[16];
  __shared__ int isLast;
  int tid = threadIdx.x;
  if (tid == 0) isLast = 0;
  int i = blockIdx.x * 1024 + tid;
  int v = (i < N) ? cnt[i] : 0;
  int lane = tid & 63;
  int incl = v;
  #pragma unroll
  for (int s = 1; s < 64; s <<= 1) {
    int t = __shfl_up(incl, s, 64);
    if (lane >= s) incl += t;
  }
  int w = tid >> 6;
  if (lane == 63) wsum[w] = incl;
  __syncthreads();
  if (w == 0) {
    int x = (lane < 16) ? wsum[lane] : 0;
    #pragma unroll
    for (int s = 1; s < 16; s <<= 1) {
      int t = __shfl_up(x, s, 64);
      if (lane >= s) x += t;
    }
    if (lane < 16) wsum[lane] = x;
  }
  __syncthreads();
  int wpre = (w == 0) ? 0 : wsum[w - 1];
  if (i < N) off[i] = wpre + incl - v;          // block-local exclusive

  if (tid == 1023) {
    atomicExch(&bsum[blockIdx.x], wpre + incl); // publish block total
    __threadfence();
    if (atomicAdd(sync, 1) == (int)gridDim.x - 1) isLast = 1;
  }
  __syncthreads();
  if (isLast && tid < 64) {                     // wave 0 of last block
    int nb = gridDim.x;                         // <= 64 for N <= 65536
    int bv = (tid < nb) ? atomicAdd(&bsum[tid], 0) : 0;  // coherent read
    int binc = bv;
    #pragma unroll
    for (int s = 1; s < 64; s <<= 1) {
      int t = __shfl_up(binc, s, 64);
      if (lane >= s) binc += t;
    }
    if (tid < nb) atomicExch(&bsum[tid], binc - bv);     // exclusive, publish
  }
}

// CSR record: x=src, y=(w1|w0) bf16 pair, z=(w3|w2) bf16 pair, w=0.
__global__ __launch_bounds__(256) void fill_kernel(
    const int* __restrict__ dst, const int* __restrict__ src,
    const float* __restrict__ ew, const int* __restrict__ off,
    const int* __restrict__ bsum, int* __restrict__ cnt,
    uint4* __restrict__ rec, int E) {
  int e = blockIdx.x * 256 + threadIdx.x;
  if (e < E) {
    int d = dst[e];
    int pos = off[d] + bsum[d >> 10] + atomicSub(&cnt[d], 1) - 1;
    unsigned w0 = f2bf(ew[e]),         w1 = f2bf(ew[E + e]);
    unsigned w2 = f2bf(ew[2 * E + e]), w3 = f2bf(ew[3 * E + e]);
    uint4 r;
    r.x = (unsigned)src[e];
    r.y = (w1 << 16) | w0;
    r.z = (w3 << 16) | w2;
    r.w = 0;
    rec[pos] = r;
  }
}

// One wave per node; lane r: t=r>>4, q=r&15. 8-wide unrolled gather (+4/+1 tails).
// n/beg/end wave-uniform via readfirstlane -> rec loads scalarize (s_load).
__global__ __launch_bounds__(256) void gather_bf16_kernel(
    const ushort4* __restrict__ nfb, const uint4* __restrict__ rec,
    const int* __restrict__ off, const int* __restrict__ bsum,
    const float4* __restrict__ bias4, float4* __restrict__ out4, int N, int E) {
  int idx = blockIdx.x * 256 + threadIdx.x;
  int n = idx >> 6;
  if (n >= N) return;
  n = __builtin_amdgcn_readfirstlane(n);
  int r = idx & 63, t = r >> 4, q = r & 15;
  int wsel = t >> 1;
  int wshift = (t & 1) << 4;
  int beg = off[n] + bsum[n >> 10];
  int end = (n + 1 < N) ? off[n + 1] + bsum[(n + 1) >> 10] : E;
  beg = __builtin_amdgcn_readfirstlane(beg);
  end = __builtin_amdgcn_readfirstlane(end);

  float4 acc = make_float4(0.f, 0.f, 0.f, 0.f);
  int p = beg;
  for (; p + 8 <= end; p += 8) {
    uint4 rr[8];
    #pragma unroll
    for (int j = 0; j < 8; ++j) rr[j] = rec[p + j];
    float w[8];
    ushort4 v[8];
    #pragma unroll
    for (int j = 0; j < 8; ++j) {
      w[j] = __uint_as_float(((wsel ? rr[j].z : rr[j].y) >> wshift) << 16);
      v[j] = nfb[(size_t)rr[j].x * 64 + t * 16 + q];
    }
    #pragma unroll
    for (int j = 0; j < 8; ++j) {
      acc.x += w[j] * bf2f(v[j].x);
      acc.y += w[j] * bf2f(v[j].y);
      acc.z += w[j] * bf2f(v[j].z);
      acc.w += w[j] * bf2f(v[j].w);
    }
  }
  for (; p + 4 <= end; p += 4) {
    uint4 rr[4];
    #pragma unroll
    for (int j = 0; j < 4; ++j) rr[j] = rec[p + j];
    #pragma unroll
    for (int j = 0; j < 4; ++j) {
      float w = __uint_as_float(((wsel ? rr[j].z : rr[j].y) >> wshift) << 16);
      ushort4 v = nfb[(size_t)rr[j].x * 64 + t * 16 + q];
      acc.x += w * bf2f(v.x); acc.y += w * bf2f(v.y);
      acc.z += w * bf2f(v.z); acc.w += w * bf2f(v.w);
    }
  }
  for (; p < end; ++p) {
    uint4 rr = rec[p];
    float w = __uint_as_float(((wsel ? rr.z : rr.y) >> wshift) << 16);
    ushort4 v = nfb[(size_t)rr.x * 64 + t * 16 + q];
    acc.x += w * bf2f(v.x); acc.y += w * bf2f(v.y);
    acc.z += w * bf2f(v.z); acc.w += w * bf2f(v.w);
  }
  float4 b = bias4[q];
  float4 res = make_float4(acc.x + b.x, acc.y + b.y, acc.z + b.z, acc.w + b.w);
  out4[(size_t)n * 64 + t * 16 + q] = res;
}

// ---- f32 fallback path (small ws) ----
__global__ __launch_bounds__(256) void hist_kernel(
    const int* __restrict__ dst, int* __restrict__ cnt, int E) {
  int e = blockIdx.x * 256 + threadIdx.x;
  if (e < E) atomicAdd(&cnt[dst[e]], 1);
}

__global__ __launch_bounds__(256) void gather_f32_kernel(
    const float4* __restrict__ nf4, const uint4* __restrict__ rec,
    const int* __restrict__ off, const int* __restrict__ bsum,
    float4* __restrict__ h4, int N, int E) {
  int idx = blockIdx.x * 256 + threadIdx.x;
  int n = idx >> 6;
  if (n >= N) return;
  int r = idx & 63, t = r >> 4, q = r & 15;
  int wsel = t >> 1;
  int wshift = (t & 1) << 4;
  int beg = off[n] + bsum[n >> 10];
  int end = (n + 1 < N) ? off[n + 1] + bsum[(n + 1) >> 10] : E;
  float4 acc = make_float4(0.f, 0.f, 0.f, 0.f);
  for (int p = beg; p < end; ++p) {
    uint4 rr = rec[p];
    float w = __uint_as_float(((wsel ? rr.z : rr.y) >> wshift) << 16);
    float4 v = nf4[(size_t)rr.x * 64 + t * 16 + q];
    acc.x += w * v.x; acc.y += w * v.y; acc.z += w * v.z; acc.w += w * v.w;
  }
  h4[(size_t)n * 64 + t * 16 + q] = acc;
}

__global__ __launch_bounds__(256) void linear_kernel(
    float* __restrict__ h, const float* __restrict__ W,
    const float* __restrict__ bias, int nrows) {
  __shared__ float Wt[64 * 65];
  __shared__ float rows[4][64];
  int tid = threadIdx.x;
  for (int i = tid; i < 4096; i += 256) Wt[(i & 63) * 65 + (i >> 6)] = W[i];
  int rr = tid >> 6, o = tid & 63;
  float b = bias[o];
  int rbase = blockIdx.x * 32;
  for (int r0 = 0; r0 < 32; r0 += 4) {
    int row = rbase + r0 + rr;
    __syncthreads();
    if (row < nrows) rows[rr][o] = h[(size_t)row * F_DIM + o];
    __syncthreads();
    if (row < nrows) {
      float acc = b;
      #pragma unroll
      for (int f = 0; f < 64; ++f) acc += rows[rr][f] * Wt[f * 65 + o];
      h[(size_t)row * F_DIM + o] = acc;
    }
  }
}

extern "C" void kernel_launch(void* const* d_in, const int* in_sizes, int n_in,
                              void* d_out, int out_size, void* d_ws, size_t ws_size,
                              hipStream_t stream) {
  const float* nf   = (const float*)d_in[0];
  const float* ew   = (const float*)d_in[1];
  const int*   src  = (const int*)d_in[2];
  const int*   dst  = (const int*)d_in[3];
  const float* W    = (const float*)d_in[4];
  const float* bias = (const float*)d_in[5];
  float* out = (float*)d_out;

  int E = in_sizes[2];
  int N = out_size / TF;
  int nrows = out_size / F_DIM;   // N*T
  int nfelems = nrows * F_DIM;

  // ws layout: [cnt N][sync 1][off N+1][bsum 64] | rec uint4[E] | nfb (512B-aligned)
  char* wsb = (char*)d_ws;
  int* cnt  = (int*)wsb;
  int* sync = cnt + N;
  int* off  = sync + 1;
  int* bsum = off + (N + 1);
  size_t ofs = ((size_t)(2 * N + 2 + 64) * 4 + 15) & ~(size_t)15;
  uint4* rec = (uint4*)(wsb + ofs);           ofs += (size_t)E * 16;
  ofs = (ofs + 511) & ~(size_t)511;
  unsigned short* nfb = (unsigned short*)(wsb + ofs);
  size_t need_bf16 = ofs + (size_t)nfelems * 2;
  bool use_bf16 = ws_size >= need_bf16;

  (void)hipMemsetAsync(cnt, 0, (size_t)(N + 1) * sizeof(int), stream);  // cnt + sync

  int eblk = (E + 255) / 256;
  int sblk = (N + 1023) / 1024;   // <= 64 required by fused scan (N <= 65536)

  if (use_bf16) {
    transform_hist_kernel<<<1024, 256, 0, stream>>>(
        (const float4*)nf, W, nfb, nrows, dst, cnt, E);
    scan_kernel<<<sblk, 1024, 0, stream>>>(cnt, off, bsum, sync, N);
    fill_kernel<<<eblk, 256, 0, stream>>>(dst, src, ew, off, bsum, cnt, rec, E);
    gather_bf16_kernel<<<(N * 64 + 255) / 256, 256, 0, stream>>>(
        (const ushort4*)nfb, rec, off, bsum, (const float4*)bias,
        (float4*)out, N, E);
  } else {
    hist_kernel<<<eblk, 256, 0, stream>>>(dst, cnt, E);
    scan_kernel<<<sblk, 1024, 0, stream>>>(cnt, off, bsum, sync, N);
    fill_kernel<<<eblk, 256, 0, stream>>>(dst, src, ew, off, bsum, cnt, rec, E);
    gather_f32_kernel<<<(N * 64 + 255) / 256, 256, 0, stream>>>(
        (const float4*)nf, rec, off, bsum, (float4*)out, N, E);
    linear_kernel<<<(nrows + 31) / 32, 256, 0, stream>>>(out, W, bias, nrows);
  }
}